// Round 1
// 53.470 us; speedup vs baseline: 1.1098x; 1.1098x over previous
//
#include <hip/hip_runtime.h>

// Additive (Bahdanau) attention, f32.
// b=4, q=256, k=1024, emb=256, h=128, v=256.
// out  = (4,256,256)  at d_out offset 0
// attn = (4,256,1024) at d_out offset 262144
//
// tanh(Hq+Hk) = 1 - 2/(e^{2Hq}*e^{2Hk} + 1).  Projections store
// Eq = exp2(2*log2e*Hq), Ek = exp2(2*log2e*Hk).  The score inner loop
// folds FOUR h-terms into ONE rcp (quarter-rate trans is the issue-port
// bottleneck):  w0/A+w1/B+w2/C+w3/D = (n01*CD + n23*AB) * rcp(AB*CD),
// z = Wsum - 2 * sum, Wsum = sum_h w[h].

#define L2E 1.4426950408889634f

// ---------------------------------------------------------------------------
// Kernel A: projections + exp epilogue.  Eq = exp2(2L2E*(query@wq)), same Ek.
// Blocks 0..63 -> Eq (1024 rows), 64..319 -> Ek (4096 rows).
// W is staged through LDS in 64-row e-chunks (32 KB) so each block reads the
// 128 KB weight matrix from global exactly once (was: once per wave sweep).
// ---------------------------------------------------------------------------
__global__ __launch_bounds__(256) void aa_proj_kernel(
    const float* __restrict__ query, const float* __restrict__ key,
    const float* __restrict__ wq, const float* __restrict__ wk,
    float* __restrict__ Eq, float* __restrict__ Ek)
{
    __shared__ float rows_s[16 * 256];   // 16 KB
    __shared__ float w_s[64 * 128];      // 32 KB
    const int i = blockIdx.x;
    const int t = threadIdx.x;

    const float* src;
    const float* W;
    float* dst;
    if (i < 64) {
        const int r0 = i * 16;
        src = query + r0 * 256; W = wq; dst = Eq + r0 * 128;
    } else {
        const int r0 = (i - 64) * 16;
        src = key + r0 * 256; W = wk; dst = Ek + r0 * 128;
    }

#pragma unroll
    for (int j = 0; j < 4; ++j) {
        const int f = t * 4 + j * 1024;
        *(float4*)&rows_s[f] = *(const float4*)&src[f];
    }

    const int rgr = t >> 5;
    const int hg = t & 31;
    const int ri0 = rgr * 2;
    const int h0 = hg * 4;

    float acc0[4] = {0.f, 0.f, 0.f, 0.f};
    float acc1[4] = {0.f, 0.f, 0.f, 0.f};

    for (int ec = 0; ec < 256; ec += 64) {
        __syncthreads();   // first iter: covers rows_s; later: w_s readers done
#pragma unroll
        for (int j = 0; j < 8; ++j) {
            const int f = t * 4 + j * 1024;
            *(float4*)&w_s[f] = *(const float4*)&W[ec * 128 + f];
        }
        __syncthreads();

        for (int e = 0; e < 64; e += 4) {
            float a0[4], a1[4];
            *(float4*)a0 = *(const float4*)&rows_s[ri0 * 256 + ec + e];
            *(float4*)a1 = *(const float4*)&rows_s[(ri0 + 1) * 256 + ec + e];
#pragma unroll
            for (int j = 0; j < 4; ++j) {
                float w[4];
                *(float4*)w = *(const float4*)&w_s[(e + j) * 128 + h0];
#pragma unroll
                for (int c = 0; c < 4; ++c) {
                    acc0[c] = fmaf(a0[j], w[c], acc0[c]);
                    acc1[c] = fmaf(a1[j], w[c], acc1[c]);
                }
            }
        }
    }

    float o0[4], o1[4];
#pragma unroll
    for (int c = 0; c < 4; ++c) {
        o0[c] = __builtin_amdgcn_exp2f(acc0[c] * (2.0f * L2E));
        o1[c] = __builtin_amdgcn_exp2f(acc1[c] * (2.0f * L2E));
    }
    *(float4*)&dst[ri0 * 128 + h0] = *(float4*)o0;
    *(float4*)&dst[(ri0 + 1) * 128 + h0] = *(float4*)o1;
}

// ---------------------------------------------------------------------------
// Kernel B: scores z = Wsum - 2*sum_h w[h]*rcp(fma(Eq,Ek,1)).
// Tile 16q x 64k, 256 threads; thread = q-rows {2qp,2qp+1}, k-rows {kp,kp+32}.
// Quad-rcp fold: 4 h-terms share one v_rcp_f32 (13 VALU + 1 trans per 4
// elements, vs 8 VALU + 4 trans).  All denominators >= 1, products <= ~1e19:
// no overflow, no cancellation.
// ---------------------------------------------------------------------------
__global__ __launch_bounds__(256) void aa_score_kernel(
    const float* __restrict__ Eq, const float* __restrict__ Ek,
    const float* __restrict__ wv, float* __restrict__ z)
{
    __shared__ float eq_s[16 * 128];
    __shared__ float ek_s[64 * 132];
    __shared__ float wv_s[128];

    const int bid = blockIdx.x;
    const int b = bid >> 8;
    const int qt = (bid >> 4) & 15;
    const int kt = bid & 15;
    const int q0g = b * 256 + qt * 16;
    const int k0g = b * 1024 + kt * 64;
    const int t = threadIdx.x;

    const float* eqsrc = Eq + q0g * 128;
#pragma unroll
    for (int j = 0; j < 2; ++j) {
        const int f = t * 4 + j * 1024;
        *(float4*)&eq_s[f] = *(const float4*)&eqsrc[f];
    }
    const float* eksrc = Ek + k0g * 128;
#pragma unroll
    for (int j = 0; j < 8; ++j) {
        const int f = t * 4 + j * 1024;
        const int ki = f >> 7;
        const int h = f & 127;
        *(float4*)&ek_s[ki * 132 + h] = *(const float4*)&eksrc[f];
    }
    if (t < 128) wv_s[t] = wv[t];
    __syncthreads();

    float wsum = 0.f;
#pragma unroll
    for (int j = 0; j < 32; ++j) {
        float w4[4];
        *(float4*)w4 = *(const float4*)&wv_s[j * 4];
        wsum += (w4[0] + w4[1]) + (w4[2] + w4[3]);
    }

    const int qp = t >> 5;     // 0..7 -> q rows 2qp, 2qp+1
    const int kp = t & 31;     // k rows kp, kp+32
    const float* eqa = eq_s + (qp * 2) * 128;
    const float* eqb = eqa + 128;
    const float* eka = ek_s + kp * 132;
    const float* ekb = eka + 32 * 132;

    float acc00 = 0.f, acc01 = 0.f, acc10 = 0.f, acc11 = 0.f;

    // quad-rcp: sum_{j=0..3} w[j]/(x[j]*y[j]+1) with a single rcp.
    auto quad = [](const float* x, const float* y, const float* w, float& acc) {
        const float A = fmaf(x[0], y[0], 1.0f);
        const float B = fmaf(x[1], y[1], 1.0f);
        const float C = fmaf(x[2], y[2], 1.0f);
        const float D = fmaf(x[3], y[3], 1.0f);
        const float AB = A * B;
        const float CD = C * D;
        const float n01 = fmaf(w[1], A, w[0] * B);
        const float n23 = fmaf(w[3], C, w[2] * D);
        const float num = fmaf(n01, CD, n23 * AB);
        acc = fmaf(num, __builtin_amdgcn_rcpf(AB * CD), acc);
    };

#pragma unroll 4
    for (int h = 0; h < 128; h += 4) {
        float a0[4], a1[4], b0[4], b1[4], w[4];
        *(float4*)a0 = *(const float4*)(eqa + h);
        *(float4*)a1 = *(const float4*)(eqb + h);
        *(float4*)b0 = *(const float4*)(eka + h);
        *(float4*)b1 = *(const float4*)(ekb + h);
        *(float4*)w  = *(const float4*)(wv_s + h);
        quad(a0, b0, w, acc00);
        quad(a0, b1, w, acc01);
        quad(a1, b0, w, acc10);
        quad(a1, b1, w, acc11);
    }

    const int kl = kt * 64 + kp;
    float* zr0 = z + (size_t)(q0g + qp * 2) * 1024 + kl;
    float* zr1 = zr0 + 1024;
    zr0[0]  = fmaf(-2.f, acc00, wsum);
    zr0[32] = fmaf(-2.f, acc01, wsum);
    zr1[0]  = fmaf(-2.f, acc10, wsum);
    zr1[32] = fmaf(-2.f, acc11, wsum);
}

// ---------------------------------------------------------------------------
// Kernel C: row softmax over k=1024.  One block (256 thr) per (b,q) row.
// Writes attention weights `a` directly into d_out.
// ---------------------------------------------------------------------------
__global__ __launch_bounds__(256) void aa_softmax_kernel(
    const float* __restrict__ z, float* __restrict__ a)
{
    const int row = blockIdx.x;
    const int t = threadIdx.x;
    const float* zr = z + (size_t)row * 1024;

    float x[4];
    *(float4*)x = *(const float4*)&zr[t * 4];

    float m = fmaxf(fmaxf(x[0], x[1]), fmaxf(x[2], x[3]));
#pragma unroll
    for (int off = 32; off; off >>= 1) m = fmaxf(m, __shfl_xor(m, off));

    __shared__ float redm[4];
    __shared__ float reds[4];
    const int wid = t >> 6;
    if ((t & 63) == 0) redm[wid] = m;
    __syncthreads();
    m = fmaxf(fmaxf(redm[0], redm[1]), fmaxf(redm[2], redm[3]));

    float e[4];
    float s = 0.f;
#pragma unroll
    for (int j = 0; j < 4; ++j) {
        e[j] = __builtin_amdgcn_exp2f((x[j] - m) * L2E);
        s += e[j];
    }
#pragma unroll
    for (int off = 32; off; off >>= 1) s += __shfl_xor(s, off);
    if ((t & 63) == 0) reds[wid] = s;
    __syncthreads();
    s = reds[0] + reds[1] + reds[2] + reds[3];

    const float inv = __builtin_amdgcn_rcpf(s);
    float o[4];
#pragma unroll
    for (int j = 0; j < 4; ++j) o[j] = e[j] * inv;
    *(float4*)&a[(size_t)row * 1024 + t * 4] = *(float4*)o;
}

// ---------------------------------------------------------------------------
// Kernel D1: split-k PV partial, v5 (16-q tile halves value L2 traffic).
// Grid: 4b x 16qt x 8kt = 512 blocks, 256 thr = 4 waves.
// Block tile: 16q x 256v over a 128-k chunk; wave w takes k-sub [w*32,+32).
// Thread: 16q x 4v accumulators.  Per 4-k group: 4 value float4 loads (each
// coalesced 1 KB/wave) + 16 broadcast LDS b128 a-reads + 256 fmac
// -> 64 fmac per global load.  Cross-wave combine via LDS (conflict-free
// strided layout).  part layout: [bid][16 q][256 v], bid = ((b*16+qt)*8+kt).
// ---------------------------------------------------------------------------
__global__ __launch_bounds__(256) void aa_pv_partial_kernel(
    const float* __restrict__ a, const float* __restrict__ value,
    float* __restrict__ part)
{
    __shared__ float a_s[16][128];      // 8 KB
    __shared__ float red_s[4][4096];    // 64 KB
    const int bid = blockIdx.x;
    const int b  = bid >> 7;
    const int qt = (bid >> 3) & 15;
    const int kt = bid & 7;
    const int t = threadIdx.x;

    // stage a[16 rows][kt*128 .. +128) into LDS (coalesced float4 per thread)
#pragma unroll
    for (int j = 0; j < 2; ++j) {
        const int f = t * 4 + j * 1024;
        const int qs = f >> 7;
        const int k0 = f & 127;
        const float* arow = a + (size_t)(b * 256 + qt * 16 + qs) * 1024 + kt * 128;
        *(float4*)&a_s[qs][k0] = *(const float4*)&arow[k0];
    }
    __syncthreads();

    const int w = t >> 6;       // wave id, k-sub = w*32
    const int lane = t & 63;
    const int v0 = lane * 4;    // 64 lanes x 4 = 256 v
    const float* vp = value + (size_t)b * 262144
                    + (size_t)(kt * 128 + w * 32) * 256 + v0;

    float acc[16][4] = {};

#pragma unroll 2
    for (int k4 = 0; k4 < 8; ++k4) {          // 8 groups of 4 k
        float vv[4][4];
#pragma unroll
        for (int r = 0; r < 4; ++r)
            *(float4*)vv[r] = *(const float4*)(vp + (size_t)(k4 * 4 + r) * 256);
#pragma unroll
        for (int q = 0; q < 16; ++q) {
            float aq[4];
            *(float4*)aq = *(const float4*)&a_s[q][w * 32 + k4 * 4];
#pragma unroll
            for (int r = 0; r < 4; ++r)
#pragma unroll
                for (int c = 0; c < 4; ++c)
                    acc[q][c] = fmaf(aq[r], vv[r][c], acc[q][c]);
        }
    }

    // stage wave partials: red_s[w][q*256 + v]
    float* rs = &red_s[w][v0];
#pragma unroll
    for (int q = 0; q < 16; ++q)
        *(float4*)(rs + q * 256) = *(float4*)acc[q];
    __syncthreads();

    // combine 4 waves; thread t handles elems i = g*1024 + c*256 + l*4 .. +4
    // (lane-consecutive float4 -> conflict-free LDS, coalesced global write)
    const int g = t >> 6;
    const int l4 = (t & 63) * 4;
    float* po = part + (size_t)bid * 4096;
#pragma unroll
    for (int c = 0; c < 4; ++c) {
        const int i = g * 1024 + c * 256 + l4;
        float s[4];
        *(float4*)s = *(const float4*)&red_s[0][i];
#pragma unroll
        for (int ww = 1; ww < 4; ++ww) {
            float x[4];
            *(float4*)x = *(const float4*)&red_s[ww][i];
            s[0] += x[0]; s[1] += x[1]; s[2] += x[2]; s[3] += x[3];
        }
        *(float4*)(po + i) = *(float4*)s;
    }
}

// ---------------------------------------------------------------------------
// Kernel D2: fixed-order 8-way reduce of partials -> out.
// part layout: [(b*16+qt)*8+kt][16 q][256 v].
// ---------------------------------------------------------------------------
__global__ __launch_bounds__(256) void aa_pv_reduce_kernel(
    const float* __restrict__ part, float* __restrict__ out)
{
    const int idx = blockIdx.x * 256 + threadIdx.x;
    const int o = idx * 4;
    const int row = o >> 8;
    const int v = o & 255;
    const int b = row >> 8;
    const int q = row & 255;
    const int qt = q >> 4;
    const int qr = q & 15;
    const float* p = part + (size_t)((b * 16 + qt) * 8) * 4096 + qr * 256 + v;

    float s[4] = {0.f, 0.f, 0.f, 0.f};
#pragma unroll
    for (int kt = 0; kt < 8; ++kt) {
        float x[4];
        *(float4*)x = *(const float4*)(p + (size_t)kt * 4096);
        s[0] += x[0]; s[1] += x[1]; s[2] += x[2]; s[3] += x[3];
    }
    *(float4*)&out[o] = *(float4*)s;
}

// ---------------------------------------------------------------------------
extern "C" void kernel_launch(void* const* d_in, const int* in_sizes, int n_in,
                              void* d_out, int out_size, void* d_ws, size_t ws_size,
                              hipStream_t stream)
{
    const float* query = (const float*)d_in[0];  // (4,256,256)
    const float* key   = (const float*)d_in[1];  // (4,1024,256)
    const float* value = (const float*)d_in[2];  // (4,1024,256)
    const float* wq    = (const float*)d_in[3];  // (256,128)
    const float* wk    = (const float*)d_in[4];  // (256,128)
    const float* wv    = (const float*)d_in[5];  // (128,)

    float* out   = (float*)d_out;                // (4,256,256)
    float* a_out = out + 4 * 256 * 256;          // (4,256,1024)

    float* ws = (float*)d_ws;
    float* Eq   = ws;                                  // 131072 f32
    float* Ek   = ws + 131072;                         // 524288 f32
    float* z    = ws + 131072 + 524288;                // 1048576 f32
    float* part = ws + 131072 + 524288 + 1048576;      // 2097152 f32 (8 MB)

    aa_proj_kernel<<<320, 256, 0, stream>>>(query, key, wq, wk, Eq, Ek);
    aa_score_kernel<<<1024, 256, 0, stream>>>(Eq, Ek, wv, z);
    aa_softmax_kernel<<<1024, 256, 0, stream>>>(z, a_out);
    aa_pv_partial_kernel<<<512, 256, 0, stream>>>(a_out, value, part);
    aa_pv_reduce_kernel<<<256, 256, 0, stream>>>(part, out);
}